// Round 14
// baseline (3418.420 us; speedup 1.0000x reference)
//
#include <hip/hip_runtime.h>

// Inputs: fp32. Outputs: fp32 (established round 3: PASSED).

constexpr int BB = 4;
constexpr int NN = 4096;
constexpr int M1 = 2048;
constexpr int M2 = 512;

typedef float v2f __attribute__((ext_vector_type(2)));

// Exact fp32 squared distance matching numpy's (dx*dx) + (dy*dy), no fma contraction.
__device__ __forceinline__ float d2_exact(float dx, float dy) {
    return __fadd_rn(__fmul_rn(dx, dx), __fmul_rn(dy, dy));
}

// DPP with bound_ctrl=1 (invalid source lanes read 0). Zero operands lose all
// max-combines and are identity for the sorted-merge networks below (real md
// keys/values > 0), and self-merge corruption (old=own) is avoided.
template<int CTRL>
__device__ __forceinline__ unsigned dppz(unsigned v) {
    return (unsigned)__builtin_amdgcn_update_dpp(0, (int)v, CTRL, 0xF, 0xF, true);
}
template<int CTRL>
__device__ __forceinline__ unsigned long long dpp64z(unsigned long long v) {
    unsigned lo = dppz<CTRL>((unsigned)v);
    unsigned hi = dppz<CTRL>((unsigned)(v >> 32));
    return ((unsigned long long)hi << 32) | (unsigned long long)lo;
}
// (top1, top2) u64 pair combine with CTRL partner pair. Keys unique.
template<int CTRL>
__device__ __forceinline__ void pairc(unsigned long long& t1, unsigned long long& t2) {
    unsigned long long o1 = dpp64z<CTRL>(t1);
    unsigned long long o2 = dpp64z<CTRL>(t2);
    bool g = o1 > t1;
    unsigned long long m1 = g ? o1 : t1;
    unsigned long long sm = g ? t1 : o1;
    unsigned long long cn = g ? o2 : t2;
    t2 = cn > sm ? cn : sm;
    t1 = m1;
}
// sorted (v1>=v2>=v3) u32 triple merge with CTRL partner triple (zeros = identity).
template<int CTRL>
__device__ __forceinline__ void tripc(unsigned& v1, unsigned& v2, unsigned& v3) {
    unsigned o1 = dppz<CTRL>(v1), o2 = dppz<CTRL>(v2), o3 = dppz<CTRL>(v3);
    unsigned m1 = v1 > o1 ? v1 : o1, n1 = v1 > o1 ? o1 : v1;
    unsigned m2 = v2 > o2 ? v2 : o2, n2 = v2 > o2 ? o2 : v2;
    unsigned m3 = v3 > o3 ? v3 : o3;
    unsigned a = n1 > m2 ? m2 : n1;          // min(n1,m2)
    v2 = n1 > m2 ? n1 : m2;
    unsigned b = n2 > m3 ? n2 : m3;
    v3 = a > b ? a : b;
    v1 = m1;
}

// ---------------------------------------------------------------------------
// lf = tanh(tanh(x@W1+b1)@W2+b2) -> out (fp32); also
// y1[j,f] = lf_j@c1W[0:64] + zones_j*c1W[64] + pos_j@c1W[65:67] + c1b (fp32 ws)
// ---------------------------------------------------------------------------
__global__ __launch_bounds__(256) void k_lf_y1(
    const float2* __restrict__ x, const float* __restrict__ zones,
    const float* __restrict__ W1, const float* __restrict__ b1,
    const float* __restrict__ W2, const float* __restrict__ b2,
    const float* __restrict__ c1W, const float* __restrict__ c1b,
    float* __restrict__ out_lf, float* __restrict__ y1)
{
    __shared__ float sh[4][64];
    __shared__ float sl[4][64];
    int tid = threadIdx.x;
    int p = tid >> 6, f = tid & 63;
    size_t pt = (size_t)blockIdx.x * 4 + p;
    float2 xv = x[pt];
    float hid = tanhf(xv.x * W1[f] + xv.y * W1[64 + f] + b1[f]);
    sh[p][f] = hid;
    __syncthreads();
    float acc = b2[f];
#pragma unroll
    for (int c = 0; c < 64; ++c) acc += sh[p][c] * W2[c * 64 + f];
    float lf = tanhf(acc);
    sl[p][f] = lf;
    out_lf[pt * 64 + f] = lf;
    __syncthreads();
    float acc2 = c1b[f] + zones[pt] * c1W[64 * 64 + f]
               + xv.x * c1W[65 * 64 + f] + xv.y * c1W[66 * 64 + f];
#pragma unroll
    for (int c = 0; c < 64; ++c) acc2 += sl[p][c] * c1W[c * 64 + f];
    y1[pt * 64 + f] = acc2;
}

// ---------------------------------------------------------------------------
// Lazy-candidate FPS — bit-exact vs the reference scan (R13 concept; R14
// fixes the scratch-spill bug: NO dynamically-indexed register arrays).
//   md[j] = fmin(md[j], d2_exact(j, c)); argmax with FIRST-index tie-break
//   via unique u64 key = bits(md)<<32 | (0xFFFFFFFF - j).
// Full round: apply pending centers; each wave posts its top-2 keys
// (16 candidates) + 3rd-largest md value; bound B = max wave-t3. Every
// non-candidate md <= B and only decreases, so while the best remaining
// candidate's md is STRICTLY > B it is exactly the reference's next pick
// (ties among candidates resolve by the same unique ~j rule). Up to PEND
// picks per full round with no barriers between picks; first pick of each
// round is the unconditional global argmax.
// ---------------------------------------------------------------------------
template<int M, int PPT>
__device__ __forceinline__ void fps_core(
    const float2* __restrict__ src, const float2* __restrict__ PTSl,
    float2* __restrict__ centl, unsigned long long (&slk)[2][16],
    unsigned (&slv)[2][8], int tid, int lane, int wv)
{
#pragma clang fp contract(off)
    constexpr int PP2 = PPT / 2;
    constexpr int PEND = 8;
    v2f px2[PP2], py2[PP2], md2[PP2];
#pragma unroll
    for (int k = 0; k < PP2; ++k) {
        float2 a = src[tid + (2 * k) * 512];
        float2 b = src[tid + (2 * k + 1) * 512];
        px2[k] = (v2f){a.x, b.x};
        py2[k] = (v2f){a.y, b.y};
        md2[k] = (v2f){1e10f, 1e10f};
    }
    float2 c0 = src[0];
    if (tid == 0) centl[0] = c0;

    float pendx[PEND], pendy[PEND];
#pragma unroll
    for (int k = 0; k < PEND; ++k) { pendx[k] = 0.0f; pendy[k] = 0.0f; }
    pendx[0] = c0.x; pendy[0] = c0.y;
    int picks = 1;
    int it = 1;
    unsigned rc = 0;
    while (it < M) {
        int par = (int)(rc & 1u); ++rc;
        // ---- apply pending centers (static indices, predicated) ----
#pragma unroll
        for (int k = 0; k < PEND; ++k) {
            if (k < picks) {                          // wave-uniform branch
                v2f vcx = (v2f){pendx[k], pendx[k]};
                v2f vcy = (v2f){pendy[k], pendy[k]};
#pragma unroll
                for (int q = 0; q < PP2; ++q) {
                    v2f dx = px2[q] - vcx, dy = py2[q] - vcy;
                    v2f d2 = (dx * dx) + (dy * dy);   // contract off => exact rn
                    md2[q] = __builtin_elementwise_min(md2[q], d2);
                }
            }
        }
        // ---- per-lane top-2 keys + top-3 md values ----
        unsigned long long t1 = 0ull, t2 = 0ull;
        unsigned v1 = 0u, v2 = 0u, v3 = 0u;
#pragma unroll
        for (int s = 0; s < PPT; ++s) {
            float mq = (s & 1) ? md2[s >> 1].y : md2[s >> 1].x;
            unsigned mb = __float_as_uint(mq);
            unsigned long long key = ((unsigned long long)mb << 32)
                | (unsigned long long)(0xFFFFFFFFu - (unsigned)(tid + s * 512));
            bool g = key > t1;
            unsigned long long ns = g ? t1 : (key > t2 ? key : t2);
            t1 = g ? key : t1;
            t2 = ns;
            bool g1 = mb > v1, g2 = mb > v2, g3 = mb > v3;
            unsigned nv3 = g2 ? v2 : (g3 ? mb : v3);
            unsigned nv2 = g1 ? v1 : (g2 ? mb : v2);
            v1 = g1 ? mb : v1; v2 = nv2; v3 = nv3;
        }
        // ---- wave ladders -> lane 63 ----
        pairc<0x111>(t1, t2); pairc<0x112>(t1, t2); pairc<0x114>(t1, t2);
        pairc<0x118>(t1, t2); pairc<0x142>(t1, t2); pairc<0x143>(t1, t2);
        tripc<0x111>(v1, v2, v3); tripc<0x112>(v1, v2, v3); tripc<0x114>(v1, v2, v3);
        tripc<0x118>(v1, v2, v3); tripc<0x142>(v1, v2, v3); tripc<0x143>(v1, v2, v3);
        if (lane == 63) {
            slk[par][2 * wv] = t1; slk[par][2 * wv + 1] = t2;
            slv[par][wv] = v3;
        }
        __syncthreads();                   // the only barrier per full round
        // ---- extract 16 candidates + bound B (uniform broadcast reads) ----
        float cmd[16], cpx[16], cpy[16];
        unsigned clo[16];
        unsigned B = 0u;
#pragma unroll
        for (int w = 0; w < 8; ++w) {
            unsigned long long a = slk[par][2 * w];
            unsigned long long b = slk[par][2 * w + 1];
            cmd[2 * w]     = __uint_as_float((unsigned)(a >> 32));
            clo[2 * w]     = (unsigned)a;
            cmd[2 * w + 1] = __uint_as_float((unsigned)(b >> 32));
            clo[2 * w + 1] = (unsigned)b;
            unsigned tv = slv[par][w];
            B = tv > B ? tv : B;
        }
#pragma unroll
        for (int i = 0; i < 16; ++i) {
            float2 pp = PTSl[(int)(0xFFFFFFFFu - clo[i])];
            cpx[i] = pp.x; cpy[i] = pp.y;
        }
        float Bf = __uint_as_float(B);
        // ---- speculative pick loop (uniform, no sync, register-only) ----
        picks = 0;
        while (true) {
            float km = cmd[0];
#pragma unroll
            for (int i = 1; i < 16; ++i) km = fmaxf(km, cmd[i]);
            if (picks > 0 && !(km > Bf)) break;   // strict: conservative & safe
            unsigned klo = 0u;
#pragma unroll
            for (int i = 0; i < 16; ++i)
                klo = (cmd[i] == km && clo[i] > klo) ? clo[i] : klo;
            float kx = 0.0f, ky = 0.0f;
#pragma unroll
            for (int i = 0; i < 16; ++i) {
                bool h = clo[i] == klo;
                kx = h ? cpx[i] : kx;
                ky = h ? cpy[i] : ky;
            }
            if (tid == 0) centl[it] = make_float2(kx, ky);
#pragma unroll
            for (int k = 0; k < PEND; ++k)         // static-index select write
                if (k == picks) { pendx[k] = kx; pendy[k] = ky; }
            ++picks; ++it;
            if (it >= M || picks >= PEND) break;
            // remove winner; update remaining candidates' md (exact rn math)
#pragma unroll
            for (int i = 0; i < 16; ++i) {
                float dx = cpx[i] - kx, dy = cpy[i] - ky;
                float d2 = (dx * dx) + (dy * dy);
                float nm = fminf(cmd[i], d2);
                cmd[i] = (clo[i] == klo) ? -1.0f : nm;
            }
        }
    }
}

// ---------------------------------------------------------------------------
// Fused FPS stage1 (4096 -> 2048) + stage2 (2048 -> 512); stage2 input is
// stage1's LDS-resident cent1. launch_bounds(512,1): candidate arrays need
// ~130 VGPRs; occupancy is irrelevant (4 blocks, latency-bound) — avoid the
// R13 scratch spill at all costs.
// ---------------------------------------------------------------------------
__global__ __launch_bounds__(512, 1) void k_fps_fused(
    const float2* __restrict__ pos, float* __restrict__ p1out,
    float* __restrict__ p2out)
{
    __shared__ float2 PTS[NN];            // 32 KB
    __shared__ float2 cent1[M1];          // 16 KB
    __shared__ float2 cent2[M2];          // 4 KB
    __shared__ unsigned long long slk[2][16];
    __shared__ unsigned slv[2][8];
    int tid = threadIdx.x, lane = tid & 63, wv = tid >> 6;
    const float2* p = pos + (size_t)blockIdx.x * NN;

    for (int i = tid; i < NN; i += 512) PTS[i] = p[i];
    __syncthreads();                      // PTS complete

    fps_core<M1, NN / 512>(p, PTS, cent1, slk, slv, tid, lane, wv);
    __syncthreads();                      // cent1 complete
    float2* o1 = (float2*)(p1out + (size_t)blockIdx.x * M1 * 2);
    for (int i = tid; i < M1; i += 512) o1[i] = cent1[i];

    fps_core<M2, M1 / 512>(cent1, cent1, cent2, slk, slv, tid, lane, wv);
    __syncthreads();                      // cent2 complete
    float2* o2 = (float2*)(p2out + (size_t)blockIdx.x * M2 * 2);
    for (int i = tid; i < M2; i += 512) o2[i] = cent2[i];
}

// ---------------------------------------------------------------------------
// Set abstraction: h[i,f] = max_{j: d2(j,i)<=r2} y[j,f]  -  ctr_i @ W_rel.
// ---------------------------------------------------------------------------
__global__ __launch_bounds__(256) void k_sa(
    const float2* __restrict__ candpos, const float* __restrict__ y,
    const float* __restrict__ ctr, const float* __restrict__ W,
    int NP, int F, int relrow, float r2, float* __restrict__ hout)
{
    __shared__ int cnt;
    __shared__ int list[4096];
    int tid = threadIdx.x;
    int b = blockIdx.y;
    size_t crow = (size_t)b * gridDim.x + blockIdx.x;
    if (tid == 0) cnt = 0;
    __syncthreads();
    float cx = ctr[crow * 2], cy = ctr[crow * 2 + 1];
    const float2* cp = candpos + (size_t)b * NP;
    for (int j = tid; j < NP; j += 256) {
        float2 pj = cp[j];
        float d2 = d2_exact(pj.x - cx, pj.y - cy);
        if (d2 <= r2) { int t = atomicAdd(&cnt, 1); list[t] = j; }
    }
    __syncthreads();
    int n = cnt;
    for (int f = tid; f < F; f += 256) {
        float m = -3.0e38f;
        for (int t = 0; t < n; ++t)
            m = fmaxf(m, y[((size_t)b * NP + list[t]) * F + f]);
        float ct = cx * W[(size_t)relrow * F + f] + cy * W[(size_t)(relrow + 1) * F + f];
        hout[crow * F + f] = m - ct;
    }
}

// ---------------------------------------------------------------------------
// y2[j,f] = h1_j @ c2W[0:64] + pos_j @ c2W[64:66] + c2b
// ---------------------------------------------------------------------------
__global__ __launch_bounds__(128) void k_y2(
    const float* __restrict__ h1, const float* __restrict__ p1,
    const float* __restrict__ W, const float* __restrict__ bb,
    float* __restrict__ y2)
{
    __shared__ float sh[64];
    size_t row = blockIdx.x;
    int f = threadIdx.x;
    if (f < 64) sh[f] = h1[row * 64 + f];
    __syncthreads();
    float acc = bb[f] + p1[row * 2] * W[64 * 128 + f]
              + p1[row * 2 + 1] * W[65 * 128 + f];
#pragma unroll
    for (int c = 0; c < 64; ++c) acc += sh[c] * W[c * 128 + f];
    y2[row * 128 + f] = acc;
}

// ---------------------------------------------------------------------------
// g[i,f] = [h2_i, pos_i] @ c3W + c3b; partial max over 8 rows/thread.
// ---------------------------------------------------------------------------
__global__ __launch_bounds__(256) void k_g(
    const float* __restrict__ h2, const float* __restrict__ p2,
    const float* __restrict__ W3, const float* __restrict__ b3,
    float* __restrict__ part)
{
    int f = blockIdx.x * 256 + threadIdx.x;
    int b = blockIdx.z;
    int i0 = blockIdx.y * 8;
    float acc[8];
    float bbv = b3[f];
#pragma unroll
    for (int ii = 0; ii < 8; ++ii) acc[ii] = bbv;
    const float* hrow = h2 + ((size_t)b * M2 + i0) * 128;
    for (int c = 0; c < 128; ++c) {
        float w = W3[(size_t)c * 1024 + f];
#pragma unroll
        for (int ii = 0; ii < 8; ++ii) acc[ii] += hrow[ii * 128 + c] * w;
    }
    float wx = W3[(size_t)128 * 1024 + f];
    float wy = W3[(size_t)129 * 1024 + f];
    const float* prow = p2 + ((size_t)b * M2 + i0) * 2;
    float m = -3.0e38f;
#pragma unroll
    for (int ii = 0; ii < 8; ++ii) {
        float g = acc[ii] + prow[ii * 2] * wx + prow[ii * 2 + 1] * wy;
        m = fmaxf(m, g);
    }
    part[((size_t)b * 64 + blockIdx.y) * 1024 + f] = m;
}

__global__ __launch_bounds__(256) void k_gmax(const float* __restrict__ part,
                                              float* __restrict__ outg)
{
    int f = blockIdx.x * 256 + threadIdx.x;   // 0..4095
    int b = f >> 10, fl = f & 1023;
    float m = -3.0e38f;
#pragma unroll 8
    for (int ig = 0; ig < 64; ++ig)
        m = fmaxf(m, part[((size_t)b * 64 + ig) * 1024 + fl]);
    outg[f] = m;
}

extern "C" void kernel_launch(void* const* d_in, const int* in_sizes, int n_in,
                              void* d_out, int out_size, void* d_ws, size_t ws_size,
                              hipStream_t stream)
{
    const float* x    = (const float*)d_in[0];
    const float* zon  = (const float*)d_in[1];
    const float* lfW1 = (const float*)d_in[2];
    const float* lfb1 = (const float*)d_in[3];
    const float* lfW2 = (const float*)d_in[4];
    const float* lfb2 = (const float*)d_in[5];
    const float* c1W  = (const float*)d_in[6];
    const float* c1b  = (const float*)d_in[7];
    const float* c2W  = (const float*)d_in[8];
    const float* c2b  = (const float*)d_in[9];
    const float* c3W  = (const float*)d_in[10];
    const float* c3b  = (const float*)d_in[11];
    float* out = (float*)d_out;

    // Workspace (fp32). "big" (4 MB) reused: y1 -> y2 -> part.
    char* w = (char*)d_ws;
    float* big = (float*)w;                    w += (size_t)BB * NN * 64 * 4;   // 4 MB
    float* p1  = (float*)w;                    w += (size_t)BB * M1 * 2 * 4;
    float* h1  = (float*)w;                    w += (size_t)BB * M1 * 64 * 4;   // 2 MB
    float* p2  = (float*)w;                    w += (size_t)BB * M2 * 2 * 4;
    float* h2  = (float*)w;                    w += (size_t)BB * M2 * 128 * 4;  // 1 MB
    float* y1 = big, * y2 = big, * part = big;

    k_lf_y1<<<BB * NN / 4, 256, 0, stream>>>((const float2*)x, zon, lfW1, lfb1,
                                             lfW2, lfb2, c1W, c1b, out, y1);
    k_fps_fused<<<BB, 512, 0, stream>>>((const float2*)x, p1, p2);
    k_sa<<<dim3(M1, BB), 256, 0, stream>>>((const float2*)x, y1, p1, c1W,
                                           NN, 64, 65, 0.25f, h1);
    k_y2<<<BB * M1, 128, 0, stream>>>(h1, p1, c2W, c2b, y2);
    k_sa<<<dim3(M2, BB), 256, 0, stream>>>((const float2*)p1, y2, p2, c2W,
                                           M1, 128, 64, 1.0f, h2);
    k_g<<<dim3(4, 64, BB), 256, 0, stream>>>(h2, p2, c3W, c3b, part);
    k_gmax<<<16, 256, 0, stream>>>(part, out + (size_t)BB * NN * 64);
}

// Round 15
// 2672.265 us; speedup vs baseline: 1.2792x; 1.2792x over previous
//
#include <hip/hip_runtime.h>

// Inputs: fp32. Outputs: fp32 (established round 3: PASSED).

constexpr int BB = 4;
constexpr int NN = 4096;
constexpr int M1 = 2048;
constexpr int M2 = 512;

typedef float v2f __attribute__((ext_vector_type(2)));

// Exact fp32 squared distance matching numpy's (dx*dx) + (dy*dy), no fma contraction.
__device__ __forceinline__ float d2_exact(float dx, float dy) {
    return __fadd_rn(__fmul_rn(dx, dx), __fmul_rn(dy, dy));
}

// DPP with bound_ctrl=1 (invalid source lanes read 0 — identity for max over
// positive keys; avoids old=own self-merge corruption in the pair network).
template<int CTRL>
__device__ __forceinline__ unsigned dppz(unsigned v) {
    return (unsigned)__builtin_amdgcn_update_dpp(0, (int)v, CTRL, 0xF, 0xF, true);
}
template<int CTRL>
__device__ __forceinline__ unsigned long long dpp64z(unsigned long long v) {
    unsigned lo = dppz<CTRL>((unsigned)v);
    unsigned hi = dppz<CTRL>((unsigned)(v >> 32));
    return ((unsigned long long)hi << 32) | (unsigned long long)lo;
}
// (top1, top2) u64 pair combine with CTRL partner pair. Keys unique. (R11/R12 proven.)
template<int CTRL>
__device__ __forceinline__ void pairc(unsigned long long& t1, unsigned long long& t2) {
    unsigned long long o1 = dpp64z<CTRL>(t1);
    unsigned long long o2 = dpp64z<CTRL>(t2);
    bool g = o1 > t1;
    unsigned long long m1 = g ? o1 : t1;
    unsigned long long sm = g ? t1 : o1;
    unsigned long long cn = g ? o2 : t2;
    t2 = cn > sm ? cn : sm;
    t1 = m1;
}

// ---------------------------------------------------------------------------
// lf = tanh(tanh(x@W1+b1)@W2+b2) -> out (fp32); also
// y1[j,f] = lf_j@c1W[0:64] + zones_j*c1W[64] + pos_j@c1W[65:67] + c1b (fp32 ws)
// ---------------------------------------------------------------------------
__global__ __launch_bounds__(256) void k_lf_y1(
    const float2* __restrict__ x, const float* __restrict__ zones,
    const float* __restrict__ W1, const float* __restrict__ b1,
    const float* __restrict__ W2, const float* __restrict__ b2,
    const float* __restrict__ c1W, const float* __restrict__ c1b,
    float* __restrict__ out_lf, float* __restrict__ y1)
{
    __shared__ float sh[4][64];
    __shared__ float sl[4][64];
    int tid = threadIdx.x;
    int p = tid >> 6, f = tid & 63;
    size_t pt = (size_t)blockIdx.x * 4 + p;
    float2 xv = x[pt];
    float hid = tanhf(xv.x * W1[f] + xv.y * W1[64 + f] + b1[f]);
    sh[p][f] = hid;
    __syncthreads();
    float acc = b2[f];
#pragma unroll
    for (int c = 0; c < 64; ++c) acc += sh[p][c] * W2[c * 64 + f];
    float lf = tanhf(acc);
    sl[p][f] = lf;
    out_lf[pt * 64 + f] = lf;
    __syncthreads();
    float acc2 = c1b[f] + zones[pt] * c1W[64 * 64 + f]
               + xv.x * c1W[65 * 64 + f] + xv.y * c1W[66 * 64 + f];
#pragma unroll
    for (int c = 0; c < 64; ++c) acc2 += sl[p][c] * c1W[c * 64 + f];
    y1[pt * 64 + f] = acc2;
}

// ---------------------------------------------------------------------------
// Lazy-candidate FPS, 8 candidates, ALL-SCALAR state (R13/R14 post-mortem:
// indexed local arrays get demoted to scratch -> serial-chain scratch reloads
// tripled round time; named scalars cannot be demoted). Bit-exact vs ref:
//   md[j] = fmin(md[j], d2_exact(j, c)); argmax, FIRST-index tie-break via
//   unique u64 key = bits(md)<<32 | (0xFFFFFFFF - j).
// Round: apply pending centers; wave pair-ladder gives per-wave (top1 key,
// top2 value); slots post both; B = max wave-top2-value. Candidates = 8 wave
// top-1s. Pick loop (uniform, register-only): first pick = exact global
// argmax (max candidate u64 key). Further picks valid while best updated
// candidate md STRICTLY > B: all md==km holders are then candidates
// (non-candidates <= B, only decreasing), updates use identical rn math,
// ties resolve by max ~j = smallest j. Up to 4 picks/round, no barriers
// between picks.
// ---------------------------------------------------------------------------
#define FC_EXTRACT(i) \
    unsigned long long kk##i = slk[par][i]; \
    float cmd##i = __uint_as_float((unsigned)(kk##i >> 32)); \
    unsigned clo##i = (unsigned)kk##i; \
    float2 pp##i = PTSl[(int)(0xFFFFFFFFu - clo##i)]; \
    float cpx##i = pp##i.x; float cpy##i = pp##i.y;
#define FC_KM(i)  km = fmaxf(km, cmd##i);
#define FC_KLO(i) klo = (cmd##i == km && clo##i > klo) ? clo##i : klo;
#define FC_KPOS(i) { bool h = clo##i == klo; kx = h ? cpx##i : kx; ky = h ? cpy##i : ky; }
#define FC_UPD(i) { float dx_ = cpx##i - kx, dy_ = cpy##i - ky; \
    float dd_ = (dx_ * dx_) + (dy_ * dy_); \
    float nm_ = fminf(cmd##i, dd_); \
    cmd##i = (clo##i == klo) ? -1.0f : nm_; }
#define FC_ALL(OP) OP(0) OP(1) OP(2) OP(3) OP(4) OP(5) OP(6) OP(7)

template<int M, int PPT>
__device__ __forceinline__ void fps_core(
    const float2* __restrict__ src, const float2* __restrict__ PTSl,
    float2* __restrict__ centl, unsigned long long (&slk)[2][8],
    unsigned (&slv)[2][8], int tid, int lane, int wv)
{
#pragma clang fp contract(off)
    constexpr int PP2 = PPT / 2;
    v2f px2[PP2], py2[PP2], md2[PP2];
#pragma unroll
    for (int k = 0; k < PP2; ++k) {
        float2 a = src[tid + (2 * k) * 512];
        float2 b = src[tid + (2 * k + 1) * 512];
        px2[k] = (v2f){a.x, b.x};
        py2[k] = (v2f){a.y, b.y};
        md2[k] = (v2f){1e10f, 1e10f};
    }
    float2 c0 = src[0];
    if (tid == 0) centl[0] = c0;

    float p0x = c0.x, p0y = c0.y, p1x = 0.f, p1y = 0.f;
    float p2x = 0.f, p2y = 0.f, p3x = 0.f, p3y = 0.f;
    int picks = 1;
    int it = 1;
    unsigned rc = 0;
    while (it < M) {
        int par = (int)(rc & 1u); ++rc;
        // ---- apply pending centers (named scalars, uniform predication) ----
#pragma unroll
        for (int k = 0; k < 4; ++k) {
            if (k < picks) {
                float ax = (k == 0) ? p0x : (k == 1) ? p1x : (k == 2) ? p2x : p3x;
                float ay = (k == 0) ? p0y : (k == 1) ? p1y : (k == 2) ? p2y : p3y;
                v2f vcx = (v2f){ax, ax}, vcy = (v2f){ay, ay};
#pragma unroll
                for (int q = 0; q < PP2; ++q) {
                    v2f dx = px2[q] - vcx, dy = py2[q] - vcy;
                    v2f d2 = (dx * dx) + (dy * dy);   // contract off => exact rn
                    md2[q] = __builtin_elementwise_min(md2[q], d2);
                }
            }
        }
        // ---- per-lane top-2 keys (R12-proven) ----
        unsigned long long t1 = 0ull, t2 = 0ull;
#pragma unroll
        for (int s = 0; s < PPT; ++s) {
            float mq = (s & 1) ? md2[s >> 1].y : md2[s >> 1].x;
            unsigned long long key = ((unsigned long long)__float_as_uint(mq) << 32)
                | (unsigned long long)(0xFFFFFFFFu - (unsigned)(tid + s * 512));
            bool g = key > t1;
            unsigned long long ns = g ? t1 : (key > t2 ? key : t2);
            t1 = g ? key : t1;
            t2 = ns;
        }
        pairc<0x111>(t1, t2); pairc<0x112>(t1, t2); pairc<0x114>(t1, t2);
        pairc<0x118>(t1, t2); pairc<0x142>(t1, t2); pairc<0x143>(t1, t2);
        if (lane == 63) {
            slk[par][wv] = t1;
            slv[par][wv] = (unsigned)(t2 >> 32);   // wave 2nd-best md value
        }
        __syncthreads();                   // the only barrier per full round
        // ---- extract 8 candidates + bound B (uniform broadcast reads) ----
        unsigned B = slv[par][0];
        B = slv[par][1] > B ? slv[par][1] : B;
        B = slv[par][2] > B ? slv[par][2] : B;
        B = slv[par][3] > B ? slv[par][3] : B;
        B = slv[par][4] > B ? slv[par][4] : B;
        B = slv[par][5] > B ? slv[par][5] : B;
        B = slv[par][6] > B ? slv[par][6] : B;
        B = slv[par][7] > B ? slv[par][7] : B;
        FC_ALL(FC_EXTRACT)
        float Bf = __uint_as_float(B);
        // ---- speculative pick loop (uniform, named-scalar registers only) ----
        picks = 0;
        while (true) {
            float km = cmd0;
            FC_KM(1) FC_KM(2) FC_KM(3) FC_KM(4) FC_KM(5) FC_KM(6) FC_KM(7)
            if (picks > 0 && !(km > Bf)) break;   // strict: conservative & safe
            unsigned klo = 0u;
            FC_ALL(FC_KLO)
            float kx = 0.0f, ky = 0.0f;
            FC_ALL(FC_KPOS)
            if (tid == 0) centl[it] = make_float2(kx, ky);
            if (picks == 0)      { p0x = kx; p0y = ky; }
            else if (picks == 1) { p1x = kx; p1y = ky; }
            else if (picks == 2) { p2x = kx; p2y = ky; }
            else                 { p3x = kx; p3y = ky; }
            ++picks; ++it;
            if (it >= M || picks >= 4) break;
            FC_ALL(FC_UPD)
        }
    }
}

// ---------------------------------------------------------------------------
// Fused FPS stage1 (4096 -> 2048) + stage2 (2048 -> 512); stage2 input is
// stage1's LDS-resident cent1.
// ---------------------------------------------------------------------------
__global__ __launch_bounds__(512, 2) void k_fps_fused(
    const float2* __restrict__ pos, float* __restrict__ p1out,
    float* __restrict__ p2out)
{
    __shared__ float2 PTS[NN];            // 32 KB
    __shared__ float2 cent1[M1];          // 16 KB
    __shared__ float2 cent2[M2];          // 4 KB
    __shared__ unsigned long long slk[2][8];
    __shared__ unsigned slv[2][8];
    int tid = threadIdx.x, lane = tid & 63, wv = tid >> 6;
    const float2* p = pos + (size_t)blockIdx.x * NN;

    for (int i = tid; i < NN; i += 512) PTS[i] = p[i];
    __syncthreads();                      // PTS complete

    fps_core<M1, NN / 512>(p, PTS, cent1, slk, slv, tid, lane, wv);
    __syncthreads();                      // cent1 complete
    float2* o1 = (float2*)(p1out + (size_t)blockIdx.x * M1 * 2);
    for (int i = tid; i < M1; i += 512) o1[i] = cent1[i];

    fps_core<M2, M1 / 512>(cent1, cent1, cent2, slk, slv, tid, lane, wv);
    __syncthreads();                      // cent2 complete
    float2* o2 = (float2*)(p2out + (size_t)blockIdx.x * M2 * 2);
    for (int i = tid; i < M2; i += 512) o2[i] = cent2[i];
}

// ---------------------------------------------------------------------------
// Set abstraction: h[i,f] = max_{j: d2(j,i)<=r2} y[j,f]  -  ctr_i @ W_rel.
// ---------------------------------------------------------------------------
__global__ __launch_bounds__(256) void k_sa(
    const float2* __restrict__ candpos, const float* __restrict__ y,
    const float* __restrict__ ctr, const float* __restrict__ W,
    int NP, int F, int relrow, float r2, float* __restrict__ hout)
{
    __shared__ int cnt;
    __shared__ int list[4096];
    int tid = threadIdx.x;
    int b = blockIdx.y;
    size_t crow = (size_t)b * gridDim.x + blockIdx.x;
    if (tid == 0) cnt = 0;
    __syncthreads();
    float cx = ctr[crow * 2], cy = ctr[crow * 2 + 1];
    const float2* cp = candpos + (size_t)b * NP;
    for (int j = tid; j < NP; j += 256) {
        float2 pj = cp[j];
        float d2 = d2_exact(pj.x - cx, pj.y - cy);
        if (d2 <= r2) { int t = atomicAdd(&cnt, 1); list[t] = j; }
    }
    __syncthreads();
    int n = cnt;
    for (int f = tid; f < F; f += 256) {
        float m = -3.0e38f;
        for (int t = 0; t < n; ++t)
            m = fmaxf(m, y[((size_t)b * NP + list[t]) * F + f]);
        float ct = cx * W[(size_t)relrow * F + f] + cy * W[(size_t)(relrow + 1) * F + f];
        hout[crow * F + f] = m - ct;
    }
}

// ---------------------------------------------------------------------------
// y2[j,f] = h1_j @ c2W[0:64] + pos_j @ c2W[64:66] + c2b
// ---------------------------------------------------------------------------
__global__ __launch_bounds__(128) void k_y2(
    const float* __restrict__ h1, const float* __restrict__ p1,
    const float* __restrict__ W, const float* __restrict__ bb,
    float* __restrict__ y2)
{
    __shared__ float sh[64];
    size_t row = blockIdx.x;
    int f = threadIdx.x;
    if (f < 64) sh[f] = h1[row * 64 + f];
    __syncthreads();
    float acc = bb[f] + p1[row * 2] * W[64 * 128 + f]
              + p1[row * 2 + 1] * W[65 * 128 + f];
#pragma unroll
    for (int c = 0; c < 64; ++c) acc += sh[c] * W[c * 128 + f];
    y2[row * 128 + f] = acc;
}

// ---------------------------------------------------------------------------
// g[i,f] = [h2_i, pos_i] @ c3W + c3b; partial max over 8 rows/thread.
// ---------------------------------------------------------------------------
__global__ __launch_bounds__(256) void k_g(
    const float* __restrict__ h2, const float* __restrict__ p2,
    const float* __restrict__ W3, const float* __restrict__ b3,
    float* __restrict__ part)
{
    int f = blockIdx.x * 256 + threadIdx.x;
    int b = blockIdx.z;
    int i0 = blockIdx.y * 8;
    float acc[8];
    float bbv = b3[f];
#pragma unroll
    for (int ii = 0; ii < 8; ++ii) acc[ii] = bbv;
    const float* hrow = h2 + ((size_t)b * M2 + i0) * 128;
    for (int c = 0; c < 128; ++c) {
        float w = W3[(size_t)c * 1024 + f];
#pragma unroll
        for (int ii = 0; ii < 8; ++ii) acc[ii] += hrow[ii * 128 + c] * w;
    }
    float wx = W3[(size_t)128 * 1024 + f];
    float wy = W3[(size_t)129 * 1024 + f];
    const float* prow = p2 + ((size_t)b * M2 + i0) * 2;
    float m = -3.0e38f;
#pragma unroll
    for (int ii = 0; ii < 8; ++ii) {
        float g = acc[ii] + prow[ii * 2] * wx + prow[ii * 2 + 1] * wy;
        m = fmaxf(m, g);
    }
    part[((size_t)b * 64 + blockIdx.y) * 1024 + f] = m;
}

__global__ __launch_bounds__(256) void k_gmax(const float* __restrict__ part,
                                              float* __restrict__ outg)
{
    int f = blockIdx.x * 256 + threadIdx.x;   // 0..4095
    int b = f >> 10, fl = f & 1023;
    float m = -3.0e38f;
#pragma unroll 8
    for (int ig = 0; ig < 64; ++ig)
        m = fmaxf(m, part[((size_t)b * 64 + ig) * 1024 + fl]);
    outg[f] = m;
}

extern "C" void kernel_launch(void* const* d_in, const int* in_sizes, int n_in,
                              void* d_out, int out_size, void* d_ws, size_t ws_size,
                              hipStream_t stream)
{
    const float* x    = (const float*)d_in[0];
    const float* zon  = (const float*)d_in[1];
    const float* lfW1 = (const float*)d_in[2];
    const float* lfb1 = (const float*)d_in[3];
    const float* lfW2 = (const float*)d_in[4];
    const float* lfb2 = (const float*)d_in[5];
    const float* c1W  = (const float*)d_in[6];
    const float* c1b  = (const float*)d_in[7];
    const float* c2W  = (const float*)d_in[8];
    const float* c2b  = (const float*)d_in[9];
    const float* c3W  = (const float*)d_in[10];
    const float* c3b  = (const float*)d_in[11];
    float* out = (float*)d_out;

    // Workspace (fp32). "big" (4 MB) reused: y1 -> y2 -> part.
    char* w = (char*)d_ws;
    float* big = (float*)w;                    w += (size_t)BB * NN * 64 * 4;   // 4 MB
    float* p1  = (float*)w;                    w += (size_t)BB * M1 * 2 * 4;
    float* h1  = (float*)w;                    w += (size_t)BB * M1 * 64 * 4;   // 2 MB
    float* p2  = (float*)w;                    w += (size_t)BB * M2 * 2 * 4;
    float* h2  = (float*)w;                    w += (size_t)BB * M2 * 128 * 4;  // 1 MB
    float* y1 = big, * y2 = big, * part = big;

    k_lf_y1<<<BB * NN / 4, 256, 0, stream>>>((const float2*)x, zon, lfW1, lfb1,
                                             lfW2, lfb2, c1W, c1b, out, y1);
    k_fps_fused<<<BB, 512, 0, stream>>>((const float2*)x, p1, p2);
    k_sa<<<dim3(M1, BB), 256, 0, stream>>>((const float2*)x, y1, p1, c1W,
                                           NN, 64, 65, 0.25f, h1);
    k_y2<<<BB * M1, 128, 0, stream>>>(h1, p1, c2W, c2b, y2);
    k_sa<<<dim3(M2, BB), 256, 0, stream>>>((const float2*)p1, y2, p2, c2W,
                                           M1, 128, 64, 1.0f, h2);
    k_g<<<dim3(4, 64, BB), 256, 0, stream>>>(h2, p2, c3W, c3b, part);
    k_gmax<<<16, 256, 0, stream>>>(part, out + (size_t)BB * NN * 64);
}

// Round 16
// 1565.321 us; speedup vs baseline: 2.1838x; 1.7072x over previous
//
#include <hip/hip_runtime.h>

// Inputs: fp32. Outputs: fp32 (established round 3: PASSED).

constexpr int BB = 4;
constexpr int NN = 4096;
constexpr int M1 = 2048;
constexpr int M2 = 512;

typedef float v2f __attribute__((ext_vector_type(2)));

// Exact fp32 squared distance matching numpy's (dx*dx) + (dy*dy), no fma contraction.
__device__ __forceinline__ float d2_exact(float dx, float dy) {
    return __fadd_rn(__fmul_rn(dx, dx), __fmul_rn(dy, dy));
}

// DPP with bound_ctrl=1 (invalid source lanes read 0 — loses all max-combines
// since real keys > 0; avoids old=own self-merge corrupting the runner-up).
template<int CTRL>
__device__ __forceinline__ unsigned long long dpp64z(unsigned long long v) {
    unsigned lo = (unsigned)__builtin_amdgcn_update_dpp(0, (int)(unsigned)v, CTRL, 0xF, 0xF, true);
    unsigned hi = (unsigned)__builtin_amdgcn_update_dpp(0, (int)(unsigned)(v >> 32), CTRL, 0xF, 0xF, true);
    return ((unsigned long long)hi << 32) | (unsigned long long)lo;
}
// (top1, top2) u64 pair combine with CTRL partner pair. Keys unique. (R11/R12 proven.)
template<int CTRL>
__device__ __forceinline__ void pairc(unsigned long long& t1, unsigned long long& t2) {
    unsigned long long o1 = dpp64z<CTRL>(t1);
    unsigned long long o2 = dpp64z<CTRL>(t2);
    bool g = o1 > t1;
    unsigned long long m1 = g ? o1 : t1;
    unsigned long long sm = g ? t1 : o1;
    unsigned long long cn = g ? o2 : t2;
    t2 = cn > sm ? cn : sm;
    t1 = m1;
}
__device__ __forceinline__ unsigned long long readlane64(unsigned long long v, int l) {
    unsigned lo = (unsigned)__builtin_amdgcn_readlane((int)(unsigned)v, l);
    unsigned hi = (unsigned)__builtin_amdgcn_readlane((int)(unsigned)(v >> 32), l);
    return ((unsigned long long)hi << 32) | (unsigned long long)lo;
}

// ---------------------------------------------------------------------------
// lf = tanh(tanh(x@W1+b1)@W2+b2) -> out (fp32); also
// y1[j,f] = lf_j@c1W[0:64] + zones_j*c1W[64] + pos_j@c1W[65:67] + c1b (fp32 ws)
// ---------------------------------------------------------------------------
__global__ __launch_bounds__(256) void k_lf_y1(
    const float2* __restrict__ x, const float* __restrict__ zones,
    const float* __restrict__ W1, const float* __restrict__ b1,
    const float* __restrict__ W2, const float* __restrict__ b2,
    const float* __restrict__ c1W, const float* __restrict__ c1b,
    float* __restrict__ out_lf, float* __restrict__ y1)
{
    __shared__ float sh[4][64];
    __shared__ float sl[4][64];
    int tid = threadIdx.x;
    int p = tid >> 6, f = tid & 63;
    size_t pt = (size_t)blockIdx.x * 4 + p;
    float2 xv = x[pt];
    float hid = tanhf(xv.x * W1[f] + xv.y * W1[64 + f] + b1[f]);
    sh[p][f] = hid;
    __syncthreads();
    float acc = b2[f];
#pragma unroll
    for (int c = 0; c < 64; ++c) acc += sh[p][c] * W2[c * 64 + f];
    float lf = tanhf(acc);
    sl[p][f] = lf;
    out_lf[pt * 64 + f] = lf;
    __syncthreads();
    float acc2 = c1b[f] + zones[pt] * c1W[64 * 64 + f]
               + xv.x * c1W[65 * 64 + f] + xv.y * c1W[66 * 64 + f];
#pragma unroll
    for (int c = 0; c < 64; ++c) acc2 += sl[p][c] * c1W[c * 64 + f];
    y1[pt * 64 + f] = acc2;
}

// ---------------------------------------------------------------------------
// FPS core, R12 structure (top-2 speculation — the only speculation variant
// that won) at 256 threads / 4 waves: per-round cost is dominated by barrier +
// cross-wave combine, which scale with wave count (R5/R6/R8: 646 ns/round at
// 256 thr vs 738-773 at 512). Bit-exact vs reference scan:
//   md[j] = fmin(md[j], d2_exact(j, c)); argmax w/ FIRST-index tie-break via
//   unique u64 key = bits(md)<<32 | (0xFFFFFFFF - j).
// If d2_exact(r1, w1) >= md_r1 the next reference pick is exactly r1 (all
// other keys < key_r1; updates only lower md; ties resolve by ~j) -> emit 2.
// ---------------------------------------------------------------------------
template<int M, int PPT>
__device__ __forceinline__ void fps_core(
    const float2* __restrict__ src, const float2* __restrict__ PTSl,
    float2* __restrict__ centl, unsigned long long (&slk)[2][8],
    int tid, int lane, int wv)
{
#pragma clang fp contract(off)
    constexpr int PP2 = PPT / 2;
    v2f px2[PP2], py2[PP2], md2[PP2];
#pragma unroll
    for (int k = 0; k < PP2; ++k) {
        float2 a = src[tid + (2 * k) * 256];
        float2 b = src[tid + (2 * k + 1) * 256];
        px2[k] = (v2f){a.x, b.x};
        py2[k] = (v2f){a.y, b.y};
        md2[k] = (v2f){1e10f, 1e10f};
    }
    float2 c0 = src[0];
    if (tid == 0) centl[0] = c0;

    float c1x = c0.x, c1y = c0.y, c2x = 0.0f, c2y = 0.0f;
    bool two = false;
    int it = 1;
    unsigned rc = 0;
    while (it < M) {
        int par = (int)(rc & 1u); ++rc;
        // ---- packed md update by pending center(s); rn per half == scalar rn
        v2f vcx = (v2f){c1x, c1x}, vcy = (v2f){c1y, c1y};
#pragma unroll
        for (int k = 0; k < PP2; ++k) {
            v2f dx = px2[k] - vcx, dy = py2[k] - vcy;
            v2f d2 = (dx * dx) + (dy * dy);          // contract off => exact
            md2[k] = __builtin_elementwise_min(md2[k], d2);
        }
        if (two) {
            v2f wcx = (v2f){c2x, c2x}, wcy = (v2f){c2y, c2y};
#pragma unroll
            for (int k = 0; k < PP2; ++k) {
                v2f dx = px2[k] - wcx, dy = py2[k] - wcy;
                v2f d2 = (dx * dx) + (dy * dy);
                md2[k] = __builtin_elementwise_min(md2[k], d2);
            }
        }
        // ---- per-lane top-2 keys ----
        unsigned long long t1 = 0ull, t2 = 0ull;
#pragma unroll
        for (int s = 0; s < PPT; ++s) {
            float mq = (s & 1) ? md2[s >> 1].y : md2[s >> 1].x;
            unsigned long long key =
                ((unsigned long long)__float_as_uint(mq) << 32)
                | (unsigned long long)(0xFFFFFFFFu - (unsigned)(tid + s * 256));
            bool g = key > t1;
            unsigned long long ns = g ? t1 : (key > t2 ? key : t2);
            t1 = g ? key : t1;
            t2 = ns;
        }
        // ---- wave pair ladder -> lane 63 ----
        pairc<0x111>(t1, t2); pairc<0x112>(t1, t2); pairc<0x114>(t1, t2);
        pairc<0x118>(t1, t2); pairc<0x142>(t1, t2); pairc<0x143>(t1, t2);
        if (lane == 63) { slk[par][2 * wv] = t1; slk[par][2 * wv + 1] = t2; }
        __syncthreads();                   // the only barrier per round
        // ---- cross-wave pair tree over 4 wave-pairs (lanes 0-3) ----
        unsigned long long a1 = slk[par][2 * (lane & 3)];
        unsigned long long a2 = slk[par][2 * (lane & 3) + 1];
        if (lane >= 4) { a1 = 0ull; a2 = 0ull; }
        pairc<0x111>(a1, a2); pairc<0x112>(a1, a2);
        unsigned long long w1 = readlane64(a1, 3);
        unsigned long long r1 = readlane64(a2, 3);
        int jw = (int)(0xFFFFFFFFu - (unsigned)w1);
        int jr = (int)(0xFFFFFFFFu - (unsigned)r1);
        float mdr = __uint_as_float((unsigned)(r1 >> 32));
        float2 wpt = PTSl[jw];             // broadcast LDS reads (independent)
        float2 rpt = PTSl[jr];
        float ddx = rpt.x - wpt.x, ddy = rpt.y - wpt.y;
        float dd = (ddx * ddx) + (ddy * ddy);    // contract off => exact rn
        bool dbl = (it + 1 < M) && (dd >= mdr);  // uniform
        if (tid == 0) { centl[it] = wpt; if (dbl) centl[it + 1] = rpt; }
        c1x = wpt.x; c1y = wpt.y; c2x = rpt.x; c2y = rpt.y;
        two = dbl;
        it += dbl ? 2 : 1;
    }
}

// ---------------------------------------------------------------------------
// Fused FPS stage1 (4096 -> 2048) + stage2 (2048 -> 512); stage2 input is
// stage1's LDS-resident cent1. 256 threads (4 waves, 1/SIMD).
// ---------------------------------------------------------------------------
__global__ __launch_bounds__(256, 1) void k_fps_fused(
    const float2* __restrict__ pos, float* __restrict__ p1out,
    float* __restrict__ p2out)
{
    __shared__ float2 PTS[NN];            // 32 KB
    __shared__ float2 cent1[M1];          // 16 KB
    __shared__ float2 cent2[M2];          // 4 KB
    __shared__ unsigned long long slk[2][8];
    int tid = threadIdx.x, lane = tid & 63, wv = tid >> 6;
    const float2* p = pos + (size_t)blockIdx.x * NN;

    for (int i = tid; i < NN; i += 256) PTS[i] = p[i];
    __syncthreads();                      // PTS complete

    fps_core<M1, NN / 256>(p, PTS, cent1, slk, tid, lane, wv);
    __syncthreads();                      // cent1 complete
    float2* o1 = (float2*)(p1out + (size_t)blockIdx.x * M1 * 2);
    for (int i = tid; i < M1; i += 256) o1[i] = cent1[i];

    fps_core<M2, M1 / 256>(cent1, cent1, cent2, slk, tid, lane, wv);
    __syncthreads();                      // cent2 complete
    float2* o2 = (float2*)(p2out + (size_t)blockIdx.x * M2 * 2);
    for (int i = tid; i < M2; i += 256) o2[i] = cent2[i];
}

// ---------------------------------------------------------------------------
// Set abstraction: h[i,f] = max_{j: d2(j,i)<=r2} y[j,f]  -  ctr_i @ W_rel.
// ---------------------------------------------------------------------------
__global__ __launch_bounds__(256) void k_sa(
    const float2* __restrict__ candpos, const float* __restrict__ y,
    const float* __restrict__ ctr, const float* __restrict__ W,
    int NP, int F, int relrow, float r2, float* __restrict__ hout)
{
    __shared__ int cnt;
    __shared__ int list[4096];
    int tid = threadIdx.x;
    int b = blockIdx.y;
    size_t crow = (size_t)b * gridDim.x + blockIdx.x;
    if (tid == 0) cnt = 0;
    __syncthreads();
    float cx = ctr[crow * 2], cy = ctr[crow * 2 + 1];
    const float2* cp = candpos + (size_t)b * NP;
    for (int j = tid; j < NP; j += 256) {
        float2 pj = cp[j];
        float d2 = d2_exact(pj.x - cx, pj.y - cy);
        if (d2 <= r2) { int t = atomicAdd(&cnt, 1); list[t] = j; }
    }
    __syncthreads();
    int n = cnt;
    for (int f = tid; f < F; f += 256) {
        float m = -3.0e38f;
        for (int t = 0; t < n; ++t)
            m = fmaxf(m, y[((size_t)b * NP + list[t]) * F + f]);
        float ct = cx * W[(size_t)relrow * F + f] + cy * W[(size_t)(relrow + 1) * F + f];
        hout[crow * F + f] = m - ct;
    }
}

// ---------------------------------------------------------------------------
// y2[j,f] = h1_j @ c2W[0:64] + pos_j @ c2W[64:66] + c2b
// ---------------------------------------------------------------------------
__global__ __launch_bounds__(128) void k_y2(
    const float* __restrict__ h1, const float* __restrict__ p1,
    const float* __restrict__ W, const float* __restrict__ bb,
    float* __restrict__ y2)
{
    __shared__ float sh[64];
    size_t row = blockIdx.x;
    int f = threadIdx.x;
    if (f < 64) sh[f] = h1[row * 64 + f];
    __syncthreads();
    float acc = bb[f] + p1[row * 2] * W[64 * 128 + f]
              + p1[row * 2 + 1] * W[65 * 128 + f];
#pragma unroll
    for (int c = 0; c < 64; ++c) acc += sh[c] * W[c * 128 + f];
    y2[row * 128 + f] = acc;
}

// ---------------------------------------------------------------------------
// g[i,f] = [h2_i, pos_i] @ c3W + c3b; partial max over 8 rows/thread.
// ---------------------------------------------------------------------------
__global__ __launch_bounds__(256) void k_g(
    const float* __restrict__ h2, const float* __restrict__ p2,
    const float* __restrict__ W3, const float* __restrict__ b3,
    float* __restrict__ part)
{
    int f = blockIdx.x * 256 + threadIdx.x;
    int b = blockIdx.z;
    int i0 = blockIdx.y * 8;
    float acc[8];
    float bbv = b3[f];
#pragma unroll
    for (int ii = 0; ii < 8; ++ii) acc[ii] = bbv;
    const float* hrow = h2 + ((size_t)b * M2 + i0) * 128;
    for (int c = 0; c < 128; ++c) {
        float w = W3[(size_t)c * 1024 + f];
#pragma unroll
        for (int ii = 0; ii < 8; ++ii) acc[ii] += hrow[ii * 128 + c] * w;
    }
    float wx = W3[(size_t)128 * 1024 + f];
    float wy = W3[(size_t)129 * 1024 + f];
    const float* prow = p2 + ((size_t)b * M2 + i0) * 2;
    float m = -3.0e38f;
#pragma unroll
    for (int ii = 0; ii < 8; ++ii) {
        float g = acc[ii] + prow[ii * 2] * wx + prow[ii * 2 + 1] * wy;
        m = fmaxf(m, g);
    }
    part[((size_t)b * 64 + blockIdx.y) * 1024 + f] = m;
}

__global__ __launch_bounds__(256) void k_gmax(const float* __restrict__ part,
                                              float* __restrict__ outg)
{
    int f = blockIdx.x * 256 + threadIdx.x;   // 0..4095
    int b = f >> 10, fl = f & 1023;
    float m = -3.0e38f;
#pragma unroll 8
    for (int ig = 0; ig < 64; ++ig)
        m = fmaxf(m, part[((size_t)b * 64 + ig) * 1024 + fl]);
    outg[f] = m;
}

extern "C" void kernel_launch(void* const* d_in, const int* in_sizes, int n_in,
                              void* d_out, int out_size, void* d_ws, size_t ws_size,
                              hipStream_t stream)
{
    const float* x    = (const float*)d_in[0];
    const float* zon  = (const float*)d_in[1];
    const float* lfW1 = (const float*)d_in[2];
    const float* lfb1 = (const float*)d_in[3];
    const float* lfW2 = (const float*)d_in[4];
    const float* lfb2 = (const float*)d_in[5];
    const float* c1W  = (const float*)d_in[6];
    const float* c1b  = (const float*)d_in[7];
    const float* c2W  = (const float*)d_in[8];
    const float* c2b  = (const float*)d_in[9];
    const float* c3W  = (const float*)d_in[10];
    const float* c3b  = (const float*)d_in[11];
    float* out = (float*)d_out;

    // Workspace (fp32). "big" (4 MB) reused: y1 -> y2 -> part.
    char* w = (char*)d_ws;
    float* big = (float*)w;                    w += (size_t)BB * NN * 64 * 4;   // 4 MB
    float* p1  = (float*)w;                    w += (size_t)BB * M1 * 2 * 4;
    float* h1  = (float*)w;                    w += (size_t)BB * M1 * 64 * 4;   // 2 MB
    float* p2  = (float*)w;                    w += (size_t)BB * M2 * 2 * 4;
    float* h2  = (float*)w;                    w += (size_t)BB * M2 * 128 * 4;  // 1 MB
    float* y1 = big, * y2 = big, * part = big;

    k_lf_y1<<<BB * NN / 4, 256, 0, stream>>>((const float2*)x, zon, lfW1, lfb1,
                                             lfW2, lfb2, c1W, c1b, out, y1);
    k_fps_fused<<<BB, 256, 0, stream>>>((const float2*)x, p1, p2);
    k_sa<<<dim3(M1, BB), 256, 0, stream>>>((const float2*)x, y1, p1, c1W,
                                           NN, 64, 65, 0.25f, h1);
    k_y2<<<BB * M1, 128, 0, stream>>>(h1, p1, c2W, c2b, y2);
    k_sa<<<dim3(M2, BB), 256, 0, stream>>>((const float2*)p1, y2, p2, c2W,
                                           M1, 128, 64, 1.0f, h2);
    k_g<<<dim3(4, 64, BB), 256, 0, stream>>>(h2, p2, c3W, c3b, part);
    k_gmax<<<16, 256, 0, stream>>>(part, out + (size_t)BB * NN * 64);
}